// Round 22
// baseline (338.605 us; speedup 1.0000x reference)
//
#include <hip/hip_runtime.h>

#define D_MODEL 2048
#define SEQ     2048
#define NB      2
#define NH      16
#define DH      128
#define MROWS   (NB*SEQ)   /* 4096 */
#define GK      2048       /* K dim of all GEMMs */
#define NT      (GK/64)    /* 32 K-tiles */

typedef __bf16 bf16x8 __attribute__((ext_vector_type(8)));
typedef float  f32x4  __attribute__((ext_vector_type(4)));
typedef unsigned short ushort8 __attribute__((ext_vector_type(8)));
typedef unsigned int   u32x4   __attribute__((ext_vector_type(4)));

__device__ __forceinline__ unsigned short f2bf(float f) {
  unsigned int u = __float_as_uint(f);
  u += 0x7FFFu + ((u >> 16) & 1u);
  return (unsigned short)(u >> 16);
}

__device__ __forceinline__ unsigned int cvtpk_bf16(float lo, float hi) {
  unsigned int r;
  asm("v_cvt_pk_bf16_f32 %0, %1, %2" : "=v"(r) : "v"(lo), "v"(hi));
  return r;
}

__device__ __forceinline__ void gload16(void* lds, const void* g) {
  __builtin_amdgcn_global_load_lds(
      (__attribute__((address_space(1))) void*)(g),
      (__attribute__((address_space(3))) void*)(lds), 16, 0, 0);
}

/* ---- fused cast: blocks 0-4095 = x (fp32->bf16), 4096-12287 = wq|wk|wv|wo */
__global__ __launch_bounds__(256) void cast_all(
    const float* __restrict__ x,
    const float* __restrict__ w0, const float* __restrict__ w1,
    const float* __restrict__ w2, const float* __restrict__ w3,
    unsigned short* __restrict__ xb, unsigned short* __restrict__ wb) {
  int gb = blockIdx.x;
  const float* src;
  unsigned short* dst;
  int i;
  if (gb < 4096) {
    src = x; dst = xb; i = gb * 256 + threadIdx.x;
  } else {
    int g2 = gb - 4096;
    int which = g2 >> 11;
    src = (which == 0) ? w0 : (which == 1) ? w1 : (which == 2) ? w2 : w3;
    dst = wb + (size_t)which * 4194304;
    i = (g2 & 2047) * 256 + threadIdx.x;
  }
  const float4* p = (const float4*)src;
  float4 a = p[2*i], b = p[2*i+1];
  ushort8 o;
  o[0]=f2bf(a.x); o[1]=f2bf(a.y); o[2]=f2bf(a.z); o[3]=f2bf(a.w);
  o[4]=f2bf(b.x); o[5]=f2bf(b.y); o[6]=f2bf(b.z); o[7]=f2bf(b.w);
  ((ushort8*)dst)[i] = o;
}

/* ---------------- QKV GEMM 256x192 (r17-proven counted-vmcnt pipeline).
   A-units partitioned by PHASE COVERAGE (A_first j{0,2}, A_second j{1,3});
   every read covered by a retired unit; every waited load >=2 phases old.  */
__global__ __launch_bounds__(512, 2) void gemm192(
    const unsigned short* __restrict__ A,
    const unsigned short* __restrict__ B,
    const float* __restrict__ b0, const float* __restrict__ b1,
    const float* __restrict__ b2,
    unsigned short* __restrict__ qo, unsigned short* __restrict__ ko,
    unsigned short* __restrict__ vo)
{
  __shared__ char lds[2*57344];   /* slot: A 32KB [256][64] + B 24KB [192][64] */

  const int tid  = threadIdx.x;
  const int lane = tid & 63, wid = tid >> 6;
  const int la   = lane & 15, hi = lane >> 4;
  const int wm   = wid >> 2,  wn = wid & 3;

  const int xcd = (int)blockIdx.x & 7, ii = (int)blockIdx.x >> 3;
  const int bm  = ii >> 2;
  const int bn  = xcd * 4 + (ii & 3);

  const unsigned short* Ab = A + (size_t)(bm*256) * GK;
  const unsigned short* Bb = B + (size_t)(bn*192) * GK;

  f32x4 acc[8][3];
  #pragma unroll
  for (int m = 0; m < 8; m++)
    #pragma unroll
    for (int n = 0; n < 3; n++) acc[m][n] = f32x4{0.f,0.f,0.f,0.f};

#define STG_A1J(base_, kt, J) do {                                            \
    int idx = (J)*512 + tid;                                                  \
    int row = idx >> 3;                                                       \
    int c   = (idx & 7) << 4;                                                 \
    gload16((base_) + idx*16,                                                 \
            Ab + (size_t)row*GK + (kt)*64 + ((c ^ ((row&7)<<4)) >> 1));       \
  } while (0)

#define STG_BJ(base_, kt, J0, J1) do {                                        \
    _Pragma("unroll")                                                         \
    for (int j = (J0); j < (J1); j++) {                                       \
      int idx = j*512 + tid;                                                  \
      int row = idx >> 3;                                                     \
      int c   = (idx & 7) << 4;                                               \
      gload16((base_) + 32768 + idx*16,                                       \
              Bb + (size_t)row*GK + (kt)*64 + ((c ^ ((row&7)<<4)) >> 1));     \
    }                                                                         \
  } while (0)

  STG_BJ(lds, 0, 0, 3);
  STG_A1J(lds, 0, 0); STG_A1J(lds, 0, 2);   /* A_first: rows 0-63,128-191 */
  STG_A1J(lds, 0, 1); STG_A1J(lds, 0, 3);   /* A_second: rows 64-127,192-255 */
  asm volatile("s_waitcnt vmcnt(2)" ::: "memory");
  __builtin_amdgcn_s_barrier();

  const int xr = (la & 7) << 4;

  #pragma unroll 1
  for (int t = 0; t < NT; ++t) {
    const char* sa  = lds + (t&1)*57344;
    const char* sbp = sa + 32768;
    char* nb = lds + ((t+1)&1)*57344;
    const bool pf = (t + 1 < NT);

    bf16x8 bfr[3], aq[4];

    /* ---- phase 1: (ks0, B + A rows m0-3); issue STG_B(t+1) ---- */
    #pragma unroll
    for (int n = 0; n < 3; n++)
      bfr[n] = *(const bf16x8*)(sbp + (((wn*48 + n*16 + la)*128 + hi*16) ^ xr));
    #pragma unroll
    for (int m = 0; m < 4; m++)
      aq[m] = *(const bf16x8*)(sa + (((wm*128 + m*16 + la)*128 + hi*16) ^ xr));
    if (pf) STG_BJ(nb, t+1, 0, 3);
    asm volatile("s_waitcnt lgkmcnt(0)" ::: "memory");
    __builtin_amdgcn_sched_barrier(0);
    __builtin_amdgcn_s_setprio(1);
    #pragma unroll
    for (int m = 0; m < 4; m++)
      #pragma unroll
      for (int n = 0; n < 3; n++)
        acc[m][n] = __builtin_amdgcn_mfma_f32_16x16x32_bf16(aq[m], bfr[n], acc[m][n], 0, 0, 0);
    __builtin_amdgcn_s_setprio(0);
    if (pf) asm volatile("s_waitcnt vmcnt(3)" ::: "memory");
    else    asm volatile("s_waitcnt vmcnt(0)" ::: "memory");
    __builtin_amdgcn_s_barrier();

    /* ---- phase 2: (ks0, A rows m4-7); issue STG_A_first(t+1) ---- */
    #pragma unroll
    for (int m = 0; m < 4; m++)
      aq[m] = *(const bf16x8*)(sa + (((wm*128 + (m+4)*16 + la)*128 + hi*16) ^ xr));
    if (pf) { STG_A1J(nb, t+1, 0); STG_A1J(nb, t+1, 2); }
    asm volatile("s_waitcnt lgkmcnt(0)" ::: "memory");
    __builtin_amdgcn_sched_barrier(0);
    __builtin_amdgcn_s_setprio(1);
    #pragma unroll
    for (int m = 0; m < 4; m++)
      #pragma unroll
      for (int n = 0; n < 3; n++)
        acc[m+4][n] = __builtin_amdgcn_mfma_f32_16x16x32_bf16(aq[m], bfr[n], acc[m+4][n], 0, 0, 0);
    __builtin_amdgcn_s_setprio(0);
    __builtin_amdgcn_s_barrier();

    /* ---- phase 3: (ks1, B + A rows m0-3); issue STG_A_second(t+1) ---- */
    #pragma unroll
    for (int n = 0; n < 3; n++)
      bfr[n] = *(const bf16x8*)(sbp + (((wn*48 + n*16 + la)*128 + 64 + hi*16) ^ xr));
    #pragma unroll
    for (int m = 0; m < 4; m++)
      aq[m] = *(const bf16x8*)(sa + (((wm*128 + m*16 + la)*128 + 64 + hi*16) ^ xr));
    if (pf) { STG_A1J(nb, t+1, 1); STG_A1J(nb, t+1, 3); }
    asm volatile("s_waitcnt lgkmcnt(0)" ::: "memory");
    __builtin_amdgcn_sched_barrier(0);
    __builtin_amdgcn_s_setprio(1);
    #pragma unroll
    for (int m = 0; m < 4; m++)
      #pragma unroll
      for (int n = 0; n < 3; n++)
        acc[m][n] = __builtin_amdgcn_mfma_f32_16x16x32_bf16(aq[m], bfr[n], acc[m][n], 0, 0, 0);
    __builtin_amdgcn_s_setprio(0);
    __builtin_amdgcn_s_barrier();

    /* ---- phase 4: (ks1, A rows m4-7) ---- */
    #pragma unroll
    for (int m = 0; m < 4; m++)
      aq[m] = *(const bf16x8*)(sa + (((wm*128 + (m+4)*16 + la)*128 + 64 + hi*16) ^ xr));
    asm volatile("s_waitcnt lgkmcnt(0)" ::: "memory");
    __builtin_amdgcn_sched_barrier(0);
    __builtin_amdgcn_s_setprio(1);
    #pragma unroll
    for (int m = 0; m < 4; m++)
      #pragma unroll
      for (int n = 0; n < 3; n++)
        acc[m+4][n] = __builtin_amdgcn_mfma_f32_16x16x32_bf16(aq[m], bfr[n], acc[m+4][n], 0, 0, 0);
    __builtin_amdgcn_s_setprio(0);
    if (pf) asm volatile("s_waitcnt vmcnt(2)" ::: "memory");
    else    asm volatile("s_waitcnt vmcnt(0)" ::: "memory");
    __builtin_amdgcn_s_barrier();
  }
#undef STG_A1J
#undef STG_BJ

  const int row0 = bm*256 + wm*128;
  const int col0 = bn*192 + wn*48;
  #pragma unroll
  for (int n = 0; n < 3; n++) {
    int col = col0 + n*16 + la;
    int mat = col >> 11;
    int c   = col & 2047;
    int h   = c >> 7, d = c & 127;
    const float* bp = (mat == 0) ? b0 : (mat == 1) ? b1 : b2;
    float bv = bp[c];
    #pragma unroll
    for (int m = 0; m < 8; m++)
      #pragma unroll
      for (int r = 0; r < 4; r++) {
        int row = row0 + m*16 + hi*4 + r;
        int bb  = row >> 11, s = row & (SEQ-1);
        unsigned short val = f2bf(acc[m][n][r] + bv);
        if (mat == 0) {
          qo[((size_t)(bb*NH + h)*SEQ + s)*DH + d] = val;
        } else if (mat == 1) {
          size_t base = ((size_t)(bb*NH + h)*SEQ + (size_t)(s >> 6)*64)*DH;
          int boff = (((s & 63) << 8) + (d << 1)) ^ ((s & 7) << 4);
          ko[base + (boff >> 1)] = val;
        } else {
          size_t base = ((size_t)(bb*NH + h)*SEQ + (size_t)(s >> 6)*64)*DH;
          int boff = ((d << 7) + ((s & 63) << 1)) ^ ((d & 7) << 4);
          vo[base + (boff >> 1)] = val;
        }
      }
  }
}

/* ---------------- out-proj GEMM 128x256 (r17-proven 3-slot 2-phase) ----- */
__global__ __launch_bounds__(512, 2) void gemm256(
    const unsigned short* __restrict__ A,
    const unsigned short* __restrict__ B,
    const float* __restrict__ b0,
    float* __restrict__ fo,
    int nbnx)
{
  __shared__ char lds[3*49152];

  const int tid  = threadIdx.x;
  const int lane = tid & 63, wid = tid >> 6;
  const int la   = lane & 15, hi = lane >> 4;
  const int wm   = wid >> 2,  wn = wid & 3;

  const int xcd = (int)blockIdx.x & 7, ii = (int)blockIdx.x >> 3;
  const int bm  = ii / nbnx;
  const int bn  = xcd * nbnx + ii % nbnx;

  const unsigned short* Ab = A + (size_t)(bm*128) * GK;
  const unsigned short* Bb = B + (size_t)(bn*256) * GK;

  f32x4 acc[4][4];
  #pragma unroll
  for (int m = 0; m < 4; m++)
    #pragma unroll
    for (int n = 0; n < 4; n++) acc[m][n] = f32x4{0.f,0.f,0.f,0.f};

#define STAGE_A(slot, kt) do {                                                \
    int sb_ = (slot) * 49152;                                                 \
    _Pragma("unroll")                                                         \
    for (int j = 0; j < 2; j++) {                                             \
      int idx = j*512 + tid;                                                  \
      int row = idx >> 3;                                                     \
      int c   = (idx & 7) << 4;                                               \
      gload16(lds + sb_ + idx*16,                                             \
              Ab + (size_t)row*GK + (kt)*64 + ((c ^ ((row&7)<<4)) >> 1));     \
    }                                                                         \
  } while (0)

#define STAGE_B(slot, kt) do {                                                \
    int sb_ = (slot) * 49152;                                                 \
    _Pragma("unroll")                                                         \
    for (int j = 0; j < 4; j++) {                                             \
      int idx = j*512 + tid;                                                  \
      int row = idx >> 3;                                                     \
      int c   = (idx & 7) << 4;                                               \
      gload16(lds + sb_ + 16384 + idx*16,                                     \
              Bb + (size_t)row*GK + (kt)*64 + ((c ^ ((row&7)<<4)) >> 1));     \
    }                                                                         \
  } while (0)

  STAGE_A(0, 0); STAGE_B(0, 0);
  STAGE_A(1, 1); STAGE_B(1, 1);

  int cs = 0, ps = 2;
  const int xr = (la & 7) << 4;

  #pragma unroll 1
  for (int t = 0; t < NT; ++t) {
    if (t + 1 < NT) asm volatile("s_waitcnt vmcnt(6)" ::: "memory");
    else            asm volatile("s_waitcnt vmcnt(0)" ::: "memory");
    __builtin_amdgcn_s_barrier();

    const char* sa  = lds + cs*49152;
    const char* sbp = sa + 16384;

    bf16x8 bfr[4][2], aA[2][2];
    #pragma unroll
    for (int n = 0; n < 4; n++)
      #pragma unroll
      for (int ks = 0; ks < 2; ks++)
        bfr[n][ks] = *(const bf16x8*)(sbp + (((wn*64 + n*16 + la)*128 + ks*64 + hi*16) ^ xr));
    #pragma unroll
    for (int m = 0; m < 2; m++)
      #pragma unroll
      for (int ks = 0; ks < 2; ks++)
        aA[m][ks] = *(const bf16x8*)(sa + (((wm*64 + m*16 + la)*128 + ks*64 + hi*16) ^ xr));

    if (t + 2 < NT) STAGE_A(ps, t + 2);

    asm volatile("s_waitcnt lgkmcnt(0)" ::: "memory");
    __builtin_amdgcn_sched_barrier(0);
    __builtin_amdgcn_s_setprio(1);
    #pragma unroll
    for (int m = 0; m < 2; m++)
      #pragma unroll
      for (int n = 0; n < 4; n++)
        #pragma unroll
        for (int ks = 0; ks < 2; ks++)
          acc[m][n] = __builtin_amdgcn_mfma_f32_16x16x32_bf16(aA[m][ks], bfr[n][ks], acc[m][n], 0, 0, 0);
    __builtin_amdgcn_s_setprio(0);
    __builtin_amdgcn_s_barrier();

    bf16x8 aB[2][2];
    #pragma unroll
    for (int m = 0; m < 2; m++)
      #pragma unroll
      for (int ks = 0; ks < 2; ks++)
        aB[m][ks] = *(const bf16x8*)(sa + (((wm*64 + (m+2)*16 + la)*128 + ks*64 + hi*16) ^ xr));

    if (t + 2 < NT) STAGE_B(ps, t + 2);

    asm volatile("s_waitcnt lgkmcnt(0)" ::: "memory");
    __builtin_amdgcn_sched_barrier(0);
    __builtin_amdgcn_s_setprio(1);
    #pragma unroll
    for (int m = 0; m < 2; m++)
      #pragma unroll
      for (int n = 0; n < 4; n++)
        #pragma unroll
        for (int ks = 0; ks < 2; ks++)
          acc[m+2][n] = __builtin_amdgcn_mfma_f32_16x16x32_bf16(aB[m][ks], bfr[n][ks], acc[m+2][n], 0, 0, 0);
    __builtin_amdgcn_s_setprio(0);

    cs = cs + 1; if (cs == 3) cs = 0;
    ps = ps + 1; if (ps == 3) ps = 0;
  }
#undef STAGE_A
#undef STAGE_B

  const int row0 = bm*128 + wm*64;
  const int col0 = bn*256 + wn*64;
  #pragma unroll
  for (int n = 0; n < 4; n++) {
    int col = col0 + n*16 + la;
    float bv = b0[col];
    #pragma unroll
    for (int m = 0; m < 4; m++)
      #pragma unroll
      for (int r = 0; r < 4; r++) {
        int row = row0 + m*16 + hi*4 + r;
        fo[(size_t)row*D_MODEL + col] = acc[m][n][r] + bv;
      }
  }
}

/* ---------------- flash attention fwd (r10 math + r22 occupancy lever):
   K double-buffered (32KB), V SINGLE-buffered (16KB) -> LDS 48KB ->
   3 blocks/CU (12 waves, +50% TLP). Per tile: issue V(t) then K(t+1);
   mid-tile vmcnt(4)+s_barrier before PV retires V(t) (oldest 4, in-order);
   end vmcnt(0)+s_barrier fences K(t+1) availability + VTs reuse.           */
__global__ __launch_bounds__(256, 3) void attn_fwd(
    const unsigned short* __restrict__ Q,
    const unsigned short* __restrict__ Kg,
    const unsigned short* __restrict__ VTg,
    unsigned short* __restrict__ O)
{
  __shared__ unsigned short Ks [2][64*128];
  __shared__ unsigned short VTs[128*64];

  const int tid  = threadIdx.x;
  const int lane = tid & 63, wid = tid >> 6;
  const int la   = lane & 15, hi = lane >> 4;
  const int swz  = ((int)(blockIdx.x & 7) << 6) + ((int)blockIdx.x >> 3);
  const int bh   = swz >> 4;
  const int q0   = (swz & 15) << 7;
  const int b    = bh >> 4, h = bh & 15;

  const unsigned short* Qh = Q   + (size_t)bh * SEQ * DH;
  const unsigned short* Kh = Kg  + (size_t)bh * SEQ * DH;
  const unsigned short* Vh = VTg + (size_t)bh * SEQ * DH;

  const int qrow = q0 + wid * 32;

  bf16x8 qf[2][4];
  #pragma unroll
  for (int qi = 0; qi < 2; qi++)
    #pragma unroll
    for (int ks = 0; ks < 4; ks++)
      qf[qi][ks] = *(const bf16x8*)(Qh + (size_t)(qrow + qi*16 + la)*DH + ks*32 + hi*8);

  f32x4 o[2][8];
  float mrun[2], lrun[2];
  #pragma unroll
  for (int qi = 0; qi < 2; qi++) {
    #pragma unroll
    for (int df = 0; df < 8; df++) o[qi][df] = f32x4{0.f,0.f,0.f,0.f};
    mrun[qi] = -1e30f; lrun[qi] = 0.f;
  }

  /* prologue: stage K(0) only */
  #pragma unroll
  for (int i = 0; i < 4; i++) {
    int off = i*4096 + tid*16;
    gload16((char*)Ks[0] + off, (const char*)Kh + off);
  }
  asm volatile("s_waitcnt vmcnt(0)" ::: "memory");
  __builtin_amdgcn_s_barrier();

  /* log2-domain scale: log2(e)/sqrt(128) */
  const float sc2 = 0.1275424483f;

  #pragma unroll 1
  for (int t = 0; t < SEQ/64; ++t) {
    const int cur = t & 1;
    const bool pf = (t + 1 < SEQ/64);

    /* issue V(t) FIRST (single buffer; read at PV of this tile), then
       K(t+1) (dbuf; read at top of t+1). Oldest-first retirement lets
       vmcnt(4) below wait exactly on V(t). */
    {
      const char* vt = (const char*)(Vh + (size_t)t*(64*DH));
      #pragma unroll
      for (int i = 0; i < 4; i++) {
        int off = i*4096 + tid*16;
        gload16((char*)VTs + off, vt + off);
      }
      if (pf) {
        const char* kt = (const char*)(Kh + (size_t)(t+1)*(64*DH));
        #pragma unroll
        for (int i = 0; i < 4; i++) {
          int off = i*4096 + tid*16;
          gload16((char*)Ks[cur^1] + off, kt + off);
        }
      }
    }

    /* S^T[kv][q] = K Q^T : S[mf][qi], kv = mf*16+hi*4+r, q = qi*16+la */
    f32x4 S[4][2];
    #pragma unroll
    for (int mf = 0; mf < 4; mf++)
      #pragma unroll
      for (int qi = 0; qi < 2; qi++) S[mf][qi] = f32x4{0.f,0.f,0.f,0.f};
    #pragma unroll
    for (int ks = 0; ks < 4; ks++) {
      bf16x8 kf[4];
      #pragma unroll
      for (int mf = 0; mf < 4; mf++) {
        int boff = (((mf*16 + la) << 8) + (ks << 6) + (hi << 4)) ^ ((la & 7) << 4);
        kf[mf] = *(const bf16x8*)((const char*)Ks[cur] + boff);
      }
      #pragma unroll
      for (int mf = 0; mf < 4; mf++)
        #pragma unroll
        for (int qi = 0; qi < 2; qi++)
          S[mf][qi] = __builtin_amdgcn_mfma_f32_16x16x32_bf16(kf[mf], qf[qi][ks], S[mf][qi], 0, 0, 0);
    }

    unsigned int pf2[2][2][4];
    #pragma unroll
    for (int qi = 0; qi < 2; qi++) {
      float pm = S[0][qi][0];
      #pragma unroll
      for (int mf = 0; mf < 4; mf++)
        #pragma unroll
        for (int r = 0; r < 4; r++) pm = fmaxf(pm, S[mf][qi][r]);
      pm = fmaxf(pm, __shfl_xor(pm, 16));
      pm = fmaxf(pm, __shfl_xor(pm, 32));
      pm *= sc2;

      float mn;
      if (__all(pm <= mrun[qi] + 8.0f)) {
        mn = mrun[qi];
      } else {
        mn = fmaxf(mrun[qi], pm);
        float alpha = __builtin_amdgcn_exp2f(mrun[qi] - mn);
        mrun[qi] = mn;
        lrun[qi] *= alpha;
        #pragma unroll
        for (int r = 0; r < 4; r++) {
          float ar = __shfl(alpha, (lane & 48) | ((hi << 2) | r), 64);
          #pragma unroll
          for (int df = 0; df < 8; df++) o[qi][df][r] *= ar;
        }
      }

      float p[4][4]; float rs = 0.f;
      #pragma unroll
      for (int mf = 0; mf < 4; mf++)
        #pragma unroll
        for (int r = 0; r < 4; r++) {
          float e = __builtin_amdgcn_exp2f(fmaf(S[mf][qi][r], sc2, -mn));
          p[mf][r] = e; rs += e;
        }
      rs += __shfl_xor(rs, 16);
      rs += __shfl_xor(rs, 32);
      lrun[qi] += rs;

      unsigned int c[4][2];
      #pragma unroll
      for (int mf = 0; mf < 4; mf++) {
        c[mf][0] = cvtpk_bf16(p[mf][0], p[mf][1]);
        c[mf][1] = cvtpk_bf16(p[mf][2], p[mf][3]);
      }
      #pragma unroll
      for (int ks2 = 0; ks2 < 2; ks2++) {
        #pragma unroll
        for (int w = 0; w < 4; w++) {
          int src = la + 16*(2*(hi & 1) + (w >> 1));
          unsigned int t0 = __shfl(c[2*ks2    ][w & 1], src, 64);
          unsigned int t1 = __shfl(c[2*ks2 + 1][w & 1], src, 64);
          pf2[qi][ks2][w] = (hi >> 1) ? t1 : t0;
        }
      }
    }

    /* V(t) availability: wave-local wait on its 4 oldest loads, then
       barrier so all waves' V-writes are visible */
    if (pf) asm volatile("s_waitcnt vmcnt(4)" ::: "memory");
    else    asm volatile("s_waitcnt vmcnt(0)" ::: "memory");
    __builtin_amdgcn_s_barrier();

    #pragma unroll
    for (int ks2 = 0; ks2 < 2; ks2++) {
      #pragma unroll
      for (int df = 0; df < 8; df++) {
        int vrow = df*16 + la;
        int boff = ((vrow << 7) + (ks2 << 6) + (hi << 4)) ^ ((la & 7) << 4);
        bf16x8 vf = *(const bf16x8*)((const char*)VTs + boff);
        #pragma unroll
        for (int qi = 0; qi < 2; qi++) {
          u32x4 pw = {pf2[qi][ks2][0], pf2[qi][ks2][1], pf2[qi][ks2][2], pf2[qi][ks2][3]};
          o[qi][df] = __builtin_amdgcn_mfma_f32_16x16x32_bf16(
              __builtin_bit_cast(bf16x8, pw), vf, o[qi][df], 0, 0, 0);
        }
      }
    }

    /* end fence: K(t+1) landed (issued ~full tile ago) + all waves done
       reading VTs before t+1 overwrites it */
    asm volatile("s_waitcnt vmcnt(0)" ::: "memory");
    __builtin_amdgcn_s_barrier();
  }

  unsigned short* Ob = O + (size_t)b * SEQ * D_MODEL + h * DH;
  #pragma unroll
  for (int qi = 0; qi < 2; qi++) {
    float linv[4];
    #pragma unroll
    for (int r = 0; r < 4; r++)
      linv[r] = 1.0f / __shfl(lrun[qi], (lane & 48) | ((hi << 2) | r), 64);
    #pragma unroll
    for (int df = 0; df < 8; df++)
      #pragma unroll
      for (int r = 0; r < 4; r++) {
        int srow = qrow + qi*16 + hi*4 + r;
        Ob[(size_t)srow * D_MODEL + df*16 + la] = f2bf(o[qi][df][r] * linv[r]);
      }
  }
}

/* ---------------- launcher ---------------- */
extern "C" void kernel_launch(void* const* d_in, const int* in_sizes, int n_in,
                              void* d_out, int out_size, void* d_ws, size_t ws_size,
                              hipStream_t stream) {
  const float* x  = (const float*)d_in[0];
  const float* wq = (const float*)d_in[1];
  const float* bq = (const float*)d_in[2];
  const float* wk = (const float*)d_in[3];
  const float* bk = (const float*)d_in[4];
  const float* wv = (const float*)d_in[5];
  const float* bv = (const float*)d_in[6];
  const float* wo = (const float*)d_in[7];
  const float* bo = (const float*)d_in[8];
  float* out = (float*)d_out;

  const size_t X = (size_t)MROWS * D_MODEL;   /* 8388608  */
  const size_t W = (size_t)D_MODEL * D_MODEL; /* 4194304  */

  unsigned short* ws  = (unsigned short*)d_ws;
  unsigned short* xb  = ws;
  unsigned short* wqb = xb  + X;   /* wqb,wkb,wvb,wob contiguous */
  unsigned short* wkb = wqb + W;
  unsigned short* wvb = wkb + W;
  unsigned short* wob = wvb + W;
  unsigned short* qb  = wob + W;
  unsigned short* kb  = qb  + X;
  unsigned short* vtg = kb  + X;
  unsigned short* ab  = vtg + X;

  cast_all<<<dim3(12288), 256, 0, stream>>>(x, wq, wk, wv, wo, xb, wqb);

  /* fused QKV: M=4096, N=6144, 256x192 tiles -> 16x32 = 512 blocks */
  gemm192<<<dim3(512), 512, 0, stream>>>(xb, wqb, bq, bk, bv, qb, kb, vtg);

  attn_fwd<<<dim3(512), 256, 0, stream>>>(qb, kb, vtg, ab);

  /* out-proj: M=4096, N=2048 -> 32x8 = 256 blocks (1 exact CU-round) */
  gemm256<<<dim3(256), 512, 0, stream>>>(ab, wob, bo, out, 1);
}

// Round 23
// 269.617 us; speedup vs baseline: 1.2559x; 1.2559x over previous
//
#include <hip/hip_runtime.h>

#define D_MODEL 2048
#define SEQ     2048
#define NB      2
#define NH      16
#define DH      128
#define MROWS   (NB*SEQ)   /* 4096 */
#define GK      2048       /* K dim of all GEMMs */
#define NT      (GK/64)    /* 32 K-tiles */

typedef __bf16 bf16x8 __attribute__((ext_vector_type(8)));
typedef float  f32x4  __attribute__((ext_vector_type(4)));
typedef unsigned short ushort8 __attribute__((ext_vector_type(8)));
typedef unsigned int   u32x4   __attribute__((ext_vector_type(4)));

__device__ __forceinline__ unsigned short f2bf(float f) {
  unsigned int u = __float_as_uint(f);
  u += 0x7FFFu + ((u >> 16) & 1u);
  return (unsigned short)(u >> 16);
}

__device__ __forceinline__ unsigned int cvtpk_bf16(float lo, float hi) {
  unsigned int r;
  asm("v_cvt_pk_bf16_f32 %0, %1, %2" : "=v"(r) : "v"(lo), "v"(hi));
  return r;
}

__device__ __forceinline__ void gload16(void* lds, const void* g) {
  __builtin_amdgcn_global_load_lds(
      (__attribute__((address_space(1))) void*)(g),
      (__attribute__((address_space(3))) void*)(lds), 16, 0, 0);
}

/* ---- fused cast: blocks 0-4095 = x (fp32->bf16), 4096-12287 = wq|wk|wv|wo */
__global__ __launch_bounds__(256) void cast_all(
    const float* __restrict__ x,
    const float* __restrict__ w0, const float* __restrict__ w1,
    const float* __restrict__ w2, const float* __restrict__ w3,
    unsigned short* __restrict__ xb, unsigned short* __restrict__ wb) {
  int gb = blockIdx.x;
  const float* src;
  unsigned short* dst;
  int i;
  if (gb < 4096) {
    src = x; dst = xb; i = gb * 256 + threadIdx.x;
  } else {
    int g2 = gb - 4096;
    int which = g2 >> 11;
    src = (which == 0) ? w0 : (which == 1) ? w1 : (which == 2) ? w2 : w3;
    dst = wb + (size_t)which * 4194304;
    i = (g2 & 2047) * 256 + threadIdx.x;
  }
  const float4* p = (const float4*)src;
  float4 a = p[2*i], b = p[2*i+1];
  ushort8 o;
  o[0]=f2bf(a.x); o[1]=f2bf(a.y); o[2]=f2bf(a.z); o[3]=f2bf(a.w);
  o[4]=f2bf(b.x); o[5]=f2bf(b.y); o[6]=f2bf(b.z); o[7]=f2bf(b.w);
  ((ushort8*)dst)[i] = o;
}

/* ---------------- QKV GEMM 256x192 (r17-proven counted-vmcnt pipeline).
   A-units partitioned by PHASE COVERAGE (A_first j{0,2}, A_second j{1,3});
   every read covered by a retired unit; every waited load >=2 phases old.  */
__global__ __launch_bounds__(512, 2) void gemm192(
    const unsigned short* __restrict__ A,
    const unsigned short* __restrict__ B,
    const float* __restrict__ b0, const float* __restrict__ b1,
    const float* __restrict__ b2,
    unsigned short* __restrict__ qo, unsigned short* __restrict__ ko,
    unsigned short* __restrict__ vo)
{
  __shared__ char lds[2*57344];   /* slot: A 32KB [256][64] + B 24KB [192][64] */

  const int tid  = threadIdx.x;
  const int lane = tid & 63, wid = tid >> 6;
  const int la   = lane & 15, hi = lane >> 4;
  const int wm   = wid >> 2,  wn = wid & 3;

  const int xcd = (int)blockIdx.x & 7, ii = (int)blockIdx.x >> 3;
  const int bm  = ii >> 2;
  const int bn  = xcd * 4 + (ii & 3);

  const unsigned short* Ab = A + (size_t)(bm*256) * GK;
  const unsigned short* Bb = B + (size_t)(bn*192) * GK;

  f32x4 acc[8][3];
  #pragma unroll
  for (int m = 0; m < 8; m++)
    #pragma unroll
    for (int n = 0; n < 3; n++) acc[m][n] = f32x4{0.f,0.f,0.f,0.f};

#define STG_A1J(base_, kt, J) do {                                            \
    int idx = (J)*512 + tid;                                                  \
    int row = idx >> 3;                                                       \
    int c   = (idx & 7) << 4;                                                 \
    gload16((base_) + idx*16,                                                 \
            Ab + (size_t)row*GK + (kt)*64 + ((c ^ ((row&7)<<4)) >> 1));       \
  } while (0)

#define STG_BJ(base_, kt, J0, J1) do {                                        \
    _Pragma("unroll")                                                         \
    for (int j = (J0); j < (J1); j++) {                                       \
      int idx = j*512 + tid;                                                  \
      int row = idx >> 3;                                                     \
      int c   = (idx & 7) << 4;                                               \
      gload16((base_) + 32768 + idx*16,                                       \
              Bb + (size_t)row*GK + (kt)*64 + ((c ^ ((row&7)<<4)) >> 1));     \
    }                                                                         \
  } while (0)

  STG_BJ(lds, 0, 0, 3);
  STG_A1J(lds, 0, 0); STG_A1J(lds, 0, 2);   /* A_first: rows 0-63,128-191 */
  STG_A1J(lds, 0, 1); STG_A1J(lds, 0, 3);   /* A_second: rows 64-127,192-255 */
  asm volatile("s_waitcnt vmcnt(2)" ::: "memory");
  __builtin_amdgcn_s_barrier();

  const int xr = (la & 7) << 4;

  #pragma unroll 1
  for (int t = 0; t < NT; ++t) {
    const char* sa  = lds + (t&1)*57344;
    const char* sbp = sa + 32768;
    char* nb = lds + ((t+1)&1)*57344;
    const bool pf = (t + 1 < NT);

    bf16x8 bfr[3], aq[4];

    /* ---- phase 1: (ks0, B + A rows m0-3); issue STG_B(t+1) ---- */
    #pragma unroll
    for (int n = 0; n < 3; n++)
      bfr[n] = *(const bf16x8*)(sbp + (((wn*48 + n*16 + la)*128 + hi*16) ^ xr));
    #pragma unroll
    for (int m = 0; m < 4; m++)
      aq[m] = *(const bf16x8*)(sa + (((wm*128 + m*16 + la)*128 + hi*16) ^ xr));
    if (pf) STG_BJ(nb, t+1, 0, 3);
    asm volatile("s_waitcnt lgkmcnt(0)" ::: "memory");
    __builtin_amdgcn_sched_barrier(0);
    __builtin_amdgcn_s_setprio(1);
    #pragma unroll
    for (int m = 0; m < 4; m++)
      #pragma unroll
      for (int n = 0; n < 3; n++)
        acc[m][n] = __builtin_amdgcn_mfma_f32_16x16x32_bf16(aq[m], bfr[n], acc[m][n], 0, 0, 0);
    __builtin_amdgcn_s_setprio(0);
    if (pf) asm volatile("s_waitcnt vmcnt(3)" ::: "memory");
    else    asm volatile("s_waitcnt vmcnt(0)" ::: "memory");
    __builtin_amdgcn_s_barrier();

    /* ---- phase 2: (ks0, A rows m4-7); issue STG_A_first(t+1) ---- */
    #pragma unroll
    for (int m = 0; m < 4; m++)
      aq[m] = *(const bf16x8*)(sa + (((wm*128 + (m+4)*16 + la)*128 + hi*16) ^ xr));
    if (pf) { STG_A1J(nb, t+1, 0); STG_A1J(nb, t+1, 2); }
    asm volatile("s_waitcnt lgkmcnt(0)" ::: "memory");
    __builtin_amdgcn_sched_barrier(0);
    __builtin_amdgcn_s_setprio(1);
    #pragma unroll
    for (int m = 0; m < 4; m++)
      #pragma unroll
      for (int n = 0; n < 3; n++)
        acc[m+4][n] = __builtin_amdgcn_mfma_f32_16x16x32_bf16(aq[m], bfr[n], acc[m+4][n], 0, 0, 0);
    __builtin_amdgcn_s_setprio(0);
    __builtin_amdgcn_s_barrier();

    /* ---- phase 3: (ks1, B + A rows m0-3); issue STG_A_second(t+1) ---- */
    #pragma unroll
    for (int n = 0; n < 3; n++)
      bfr[n] = *(const bf16x8*)(sbp + (((wn*48 + n*16 + la)*128 + 64 + hi*16) ^ xr));
    #pragma unroll
    for (int m = 0; m < 4; m++)
      aq[m] = *(const bf16x8*)(sa + (((wm*128 + m*16 + la)*128 + 64 + hi*16) ^ xr));
    if (pf) { STG_A1J(nb, t+1, 1); STG_A1J(nb, t+1, 3); }
    asm volatile("s_waitcnt lgkmcnt(0)" ::: "memory");
    __builtin_amdgcn_sched_barrier(0);
    __builtin_amdgcn_s_setprio(1);
    #pragma unroll
    for (int m = 0; m < 4; m++)
      #pragma unroll
      for (int n = 0; n < 3; n++)
        acc[m][n] = __builtin_amdgcn_mfma_f32_16x16x32_bf16(aq[m], bfr[n], acc[m][n], 0, 0, 0);
    __builtin_amdgcn_s_setprio(0);
    __builtin_amdgcn_s_barrier();

    /* ---- phase 4: (ks1, A rows m4-7) ---- */
    #pragma unroll
    for (int m = 0; m < 4; m++)
      aq[m] = *(const bf16x8*)(sa + (((wm*128 + (m+4)*16 + la)*128 + 64 + hi*16) ^ xr));
    asm volatile("s_waitcnt lgkmcnt(0)" ::: "memory");
    __builtin_amdgcn_sched_barrier(0);
    __builtin_amdgcn_s_setprio(1);
    #pragma unroll
    for (int m = 0; m < 4; m++)
      #pragma unroll
      for (int n = 0; n < 3; n++)
        acc[m+4][n] = __builtin_amdgcn_mfma_f32_16x16x32_bf16(aq[m], bfr[n], acc[m+4][n], 0, 0, 0);
    __builtin_amdgcn_s_setprio(0);
    if (pf) asm volatile("s_waitcnt vmcnt(2)" ::: "memory");
    else    asm volatile("s_waitcnt vmcnt(0)" ::: "memory");
    __builtin_amdgcn_s_barrier();
  }
#undef STG_A1J
#undef STG_BJ

  const int row0 = bm*256 + wm*128;
  const int col0 = bn*192 + wn*48;
  #pragma unroll
  for (int n = 0; n < 3; n++) {
    int col = col0 + n*16 + la;
    int mat = col >> 11;
    int c   = col & 2047;
    int h   = c >> 7, d = c & 127;
    const float* bp = (mat == 0) ? b0 : (mat == 1) ? b1 : b2;
    float bv = bp[c];
    #pragma unroll
    for (int m = 0; m < 8; m++)
      #pragma unroll
      for (int r = 0; r < 4; r++) {
        int row = row0 + m*16 + hi*4 + r;
        int bb  = row >> 11, s = row & (SEQ-1);
        unsigned short val = f2bf(acc[m][n][r] + bv);
        if (mat == 0) {
          qo[((size_t)(bb*NH + h)*SEQ + s)*DH + d] = val;
        } else if (mat == 1) {
          size_t base = ((size_t)(bb*NH + h)*SEQ + (size_t)(s >> 6)*64)*DH;
          int boff = (((s & 63) << 8) + (d << 1)) ^ ((s & 7) << 4);
          ko[base + (boff >> 1)] = val;
        } else {
          size_t base = ((size_t)(bb*NH + h)*SEQ + (size_t)(s >> 6)*64)*DH;
          int boff = ((d << 7) + ((s & 63) << 1)) ^ ((d & 7) << 4);
          vo[base + (boff >> 1)] = val;
        }
      }
  }
}

/* ---------------- out-proj GEMM 128x256 (r17-proven 3-slot 2-phase) ----- */
__global__ __launch_bounds__(512, 2) void gemm256(
    const unsigned short* __restrict__ A,
    const unsigned short* __restrict__ B,
    const float* __restrict__ b0,
    float* __restrict__ fo,
    int nbnx)
{
  __shared__ char lds[3*49152];

  const int tid  = threadIdx.x;
  const int lane = tid & 63, wid = tid >> 6;
  const int la   = lane & 15, hi = lane >> 4;
  const int wm   = wid >> 2,  wn = wid & 3;

  const int xcd = (int)blockIdx.x & 7, ii = (int)blockIdx.x >> 3;
  const int bm  = ii / nbnx;
  const int bn  = xcd * nbnx + ii % nbnx;

  const unsigned short* Ab = A + (size_t)(bm*128) * GK;
  const unsigned short* Bb = B + (size_t)(bn*256) * GK;

  f32x4 acc[4][4];
  #pragma unroll
  for (int m = 0; m < 4; m++)
    #pragma unroll
    for (int n = 0; n < 4; n++) acc[m][n] = f32x4{0.f,0.f,0.f,0.f};

#define STAGE_A(slot, kt) do {                                                \
    int sb_ = (slot) * 49152;                                                 \
    _Pragma("unroll")                                                         \
    for (int j = 0; j < 2; j++) {                                             \
      int idx = j*512 + tid;                                                  \
      int row = idx >> 3;                                                     \
      int c   = (idx & 7) << 4;                                               \
      gload16(lds + sb_ + idx*16,                                             \
              Ab + (size_t)row*GK + (kt)*64 + ((c ^ ((row&7)<<4)) >> 1));     \
    }                                                                         \
  } while (0)

#define STAGE_B(slot, kt) do {                                                \
    int sb_ = (slot) * 49152;                                                 \
    _Pragma("unroll")                                                         \
    for (int j = 0; j < 4; j++) {                                             \
      int idx = j*512 + tid;                                                  \
      int row = idx >> 3;                                                     \
      int c   = (idx & 7) << 4;                                               \
      gload16(lds + sb_ + 16384 + idx*16,                                     \
              Bb + (size_t)row*GK + (kt)*64 + ((c ^ ((row&7)<<4)) >> 1));     \
    }                                                                         \
  } while (0)

  STAGE_A(0, 0); STAGE_B(0, 0);
  STAGE_A(1, 1); STAGE_B(1, 1);

  int cs = 0, ps = 2;
  const int xr = (la & 7) << 4;

  #pragma unroll 1
  for (int t = 0; t < NT; ++t) {
    if (t + 1 < NT) asm volatile("s_waitcnt vmcnt(6)" ::: "memory");
    else            asm volatile("s_waitcnt vmcnt(0)" ::: "memory");
    __builtin_amdgcn_s_barrier();

    const char* sa  = lds + cs*49152;
    const char* sbp = sa + 16384;

    bf16x8 bfr[4][2], aA[2][2];
    #pragma unroll
    for (int n = 0; n < 4; n++)
      #pragma unroll
      for (int ks = 0; ks < 2; ks++)
        bfr[n][ks] = *(const bf16x8*)(sbp + (((wn*64 + n*16 + la)*128 + ks*64 + hi*16) ^ xr));
    #pragma unroll
    for (int m = 0; m < 2; m++)
      #pragma unroll
      for (int ks = 0; ks < 2; ks++)
        aA[m][ks] = *(const bf16x8*)(sa + (((wm*64 + m*16 + la)*128 + ks*64 + hi*16) ^ xr));

    if (t + 2 < NT) STAGE_A(ps, t + 2);

    asm volatile("s_waitcnt lgkmcnt(0)" ::: "memory");
    __builtin_amdgcn_sched_barrier(0);
    __builtin_amdgcn_s_setprio(1);
    #pragma unroll
    for (int m = 0; m < 2; m++)
      #pragma unroll
      for (int n = 0; n < 4; n++)
        #pragma unroll
        for (int ks = 0; ks < 2; ks++)
          acc[m][n] = __builtin_amdgcn_mfma_f32_16x16x32_bf16(aA[m][ks], bfr[n][ks], acc[m][n], 0, 0, 0);
    __builtin_amdgcn_s_setprio(0);
    __builtin_amdgcn_s_barrier();

    bf16x8 aB[2][2];
    #pragma unroll
    for (int m = 0; m < 2; m++)
      #pragma unroll
      for (int ks = 0; ks < 2; ks++)
        aB[m][ks] = *(const bf16x8*)(sa + (((wm*64 + (m+2)*16 + la)*128 + ks*64 + hi*16) ^ xr));

    if (t + 2 < NT) STAGE_B(ps, t + 2);

    asm volatile("s_waitcnt lgkmcnt(0)" ::: "memory");
    __builtin_amdgcn_sched_barrier(0);
    __builtin_amdgcn_s_setprio(1);
    #pragma unroll
    for (int m = 0; m < 2; m++)
      #pragma unroll
      for (int n = 0; n < 4; n++)
        #pragma unroll
        for (int ks = 0; ks < 2; ks++)
          acc[m+2][n] = __builtin_amdgcn_mfma_f32_16x16x32_bf16(aB[m][ks], bfr[n][ks], acc[m+2][n], 0, 0, 0);
    __builtin_amdgcn_s_setprio(0);

    cs = cs + 1; if (cs == 3) cs = 0;
    ps = ps + 1; if (ps == 3) ps = 0;
  }
#undef STAGE_A
#undef STAGE_B

  const int row0 = bm*128 + wm*64;
  const int col0 = bn*256 + wn*64;
  #pragma unroll
  for (int n = 0; n < 4; n++) {
    int col = col0 + n*16 + la;
    float bv = b0[col];
    #pragma unroll
    for (int m = 0; m < 4; m++)
      #pragma unroll
      for (int r = 0; r < 4; r++) {
        int row = row0 + m*16 + hi*4 + r;
        fo[(size_t)row*D_MODEL + col] = acc[m][n][r] + bv;
      }
  }
}

/* ---------------- flash attention fwd (round-10 proven: T13 defer-max +
   exp2-domain softmax; K/V both double-buffered — r22 single-V failed) ---- */
__global__ __launch_bounds__(256, 2) void attn_fwd(
    const unsigned short* __restrict__ Q,
    const unsigned short* __restrict__ Kg,
    const unsigned short* __restrict__ VTg,
    unsigned short* __restrict__ O)
{
  __shared__ unsigned short Ks [2][64*128];
  __shared__ unsigned short VTs[2][128*64];

  const int tid  = threadIdx.x;
  const int lane = tid & 63, wid = tid >> 6;
  const int la   = lane & 15, hi = lane >> 4;
  const int swz  = ((int)(blockIdx.x & 7) << 6) + ((int)blockIdx.x >> 3);
  const int bh   = swz >> 4;
  const int q0   = (swz & 15) << 7;
  const int b    = bh >> 4, h = bh & 15;

  const unsigned short* Qh = Q   + (size_t)bh * SEQ * DH;
  const unsigned short* Kh = Kg  + (size_t)bh * SEQ * DH;
  const unsigned short* Vh = VTg + (size_t)bh * SEQ * DH;

  const int qrow = q0 + wid * 32;

  bf16x8 qf[2][4];
  #pragma unroll
  for (int qi = 0; qi < 2; qi++)
    #pragma unroll
    for (int ks = 0; ks < 4; ks++)
      qf[qi][ks] = *(const bf16x8*)(Qh + (size_t)(qrow + qi*16 + la)*DH + ks*32 + hi*8);

  f32x4 o[2][8];
  float mrun[2], lrun[2];
  #pragma unroll
  for (int qi = 0; qi < 2; qi++) {
    #pragma unroll
    for (int df = 0; df < 8; df++) o[qi][df] = f32x4{0.f,0.f,0.f,0.f};
    mrun[qi] = -1e30f; lrun[qi] = 0.f;
  }

  #pragma unroll
  for (int i = 0; i < 4; i++) {
    int off = i*4096 + tid*16;
    gload16((char*)Ks[0]  + off, (const char*)Kh + off);
    gload16((char*)VTs[0] + off, (const char*)Vh + off);
  }
  __syncthreads();

  /* log2-domain scale: log2(e)/sqrt(128) */
  const float sc2 = 0.1275424483f;

  #pragma unroll 1
  for (int t = 0; t < SEQ/64; ++t) {
    const int cur = t & 1;

    if (t + 1 < SEQ/64) {
      const char* kt = (const char*)(Kh + (size_t)(t+1)*(64*DH));
      const char* vt = (const char*)(Vh + (size_t)(t+1)*(64*DH));
      #pragma unroll
      for (int i = 0; i < 4; i++) {
        int off = i*4096 + tid*16;
        gload16((char*)Ks[cur^1]  + off, kt + off);
        gload16((char*)VTs[cur^1] + off, vt + off);
      }
    }

    /* S^T[kv][q] = K Q^T : S[mf][qi], kv = mf*16+hi*4+r, q = qi*16+la */
    f32x4 S[4][2];
    #pragma unroll
    for (int mf = 0; mf < 4; mf++)
      #pragma unroll
      for (int qi = 0; qi < 2; qi++) S[mf][qi] = f32x4{0.f,0.f,0.f,0.f};
    #pragma unroll
    for (int ks = 0; ks < 4; ks++) {
      bf16x8 kf[4];
      #pragma unroll
      for (int mf = 0; mf < 4; mf++) {
        int boff = (((mf*16 + la) << 8) + (ks << 6) + (hi << 4)) ^ ((la & 7) << 4);
        kf[mf] = *(const bf16x8*)((const char*)Ks[cur] + boff);
      }
      #pragma unroll
      for (int mf = 0; mf < 4; mf++)
        #pragma unroll
        for (int qi = 0; qi < 2; qi++)
          S[mf][qi] = __builtin_amdgcn_mfma_f32_16x16x32_bf16(kf[mf], qf[qi][ks], S[mf][qi], 0, 0, 0);
    }

    unsigned int pf[2][2][4];
    #pragma unroll
    for (int qi = 0; qi < 2; qi++) {
      float pm = S[0][qi][0];
      #pragma unroll
      for (int mf = 0; mf < 4; mf++)
        #pragma unroll
        for (int r = 0; r < 4; r++) pm = fmaxf(pm, S[mf][qi][r]);
      pm = fmaxf(pm, __shfl_xor(pm, 16));
      pm = fmaxf(pm, __shfl_xor(pm, 32));
      pm *= sc2;

      float mn;
      if (__all(pm <= mrun[qi] + 8.0f)) {
        mn = mrun[qi];
      } else {
        mn = fmaxf(mrun[qi], pm);
        float alpha = __builtin_amdgcn_exp2f(mrun[qi] - mn);
        mrun[qi] = mn;
        lrun[qi] *= alpha;
        #pragma unroll
        for (int r = 0; r < 4; r++) {
          float ar = __shfl(alpha, (lane & 48) | ((hi << 2) | r), 64);
          #pragma unroll
          for (int df = 0; df < 8; df++) o[qi][df][r] *= ar;
        }
      }

      float p[4][4]; float rs = 0.f;
      #pragma unroll
      for (int mf = 0; mf < 4; mf++)
        #pragma unroll
        for (int r = 0; r < 4; r++) {
          float e = __builtin_amdgcn_exp2f(fmaf(S[mf][qi][r], sc2, -mn));
          p[mf][r] = e; rs += e;
        }
      rs += __shfl_xor(rs, 16);
      rs += __shfl_xor(rs, 32);
      lrun[qi] += rs;

      unsigned int c[4][2];
      #pragma unroll
      for (int mf = 0; mf < 4; mf++) {
        c[mf][0] = cvtpk_bf16(p[mf][0], p[mf][1]);
        c[mf][1] = cvtpk_bf16(p[mf][2], p[mf][3]);
      }
      #pragma unroll
      for (int ks2 = 0; ks2 < 2; ks2++) {
        #pragma unroll
        for (int w = 0; w < 4; w++) {
          int src = la + 16*(2*(hi & 1) + (w >> 1));
          unsigned int t0 = __shfl(c[2*ks2    ][w & 1], src, 64);
          unsigned int t1 = __shfl(c[2*ks2 + 1][w & 1], src, 64);
          pf[qi][ks2][w] = (hi >> 1) ? t1 : t0;
        }
      }
    }

    #pragma unroll
    for (int ks2 = 0; ks2 < 2; ks2++) {
      #pragma unroll
      for (int df = 0; df < 8; df++) {
        int vrow = df*16 + la;
        int boff = ((vrow << 7) + (ks2 << 6) + (hi << 4)) ^ ((la & 7) << 4);
        bf16x8 vf = *(const bf16x8*)((const char*)VTs[cur] + boff);
        #pragma unroll
        for (int qi = 0; qi < 2; qi++) {
          u32x4 pw = {pf[qi][ks2][0], pf[qi][ks2][1], pf[qi][ks2][2], pf[qi][ks2][3]};
          o[qi][df] = __builtin_amdgcn_mfma_f32_16x16x32_bf16(
              __builtin_bit_cast(bf16x8, pw), vf, o[qi][df], 0, 0, 0);
        }
      }
    }
    __syncthreads();
  }

  unsigned short* Ob = O + (size_t)b * SEQ * D_MODEL + h * DH;
  #pragma unroll
  for (int qi = 0; qi < 2; qi++) {
    float linv[4];
    #pragma unroll
    for (int r = 0; r < 4; r++)
      linv[r] = 1.0f / __shfl(lrun[qi], (lane & 48) | ((hi << 2) | r), 64);
    #pragma unroll
    for (int df = 0; df < 8; df++)
      #pragma unroll
      for (int r = 0; r < 4; r++) {
        int srow = qrow + qi*16 + hi*4 + r;
        Ob[(size_t)srow * D_MODEL + df*16 + la] = f2bf(o[qi][df][r] * linv[r]);
      }
  }
}

/* ---------------- launcher ---------------- */
extern "C" void kernel_launch(void* const* d_in, const int* in_sizes, int n_in,
                              void* d_out, int out_size, void* d_ws, size_t ws_size,
                              hipStream_t stream) {
  const float* x  = (const float*)d_in[0];
  const float* wq = (const float*)d_in[1];
  const float* bq = (const float*)d_in[2];
  const float* wk = (const float*)d_in[3];
  const float* bk = (const float*)d_in[4];
  const float* wv = (const float*)d_in[5];
  const float* bv = (const float*)d_in[6];
  const float* wo = (const float*)d_in[7];
  const float* bo = (const float*)d_in[8];
  float* out = (float*)d_out;

  const size_t X = (size_t)MROWS * D_MODEL;   /* 8388608  */
  const size_t W = (size_t)D_MODEL * D_MODEL; /* 4194304  */

  unsigned short* ws  = (unsigned short*)d_ws;
  unsigned short* xb  = ws;
  unsigned short* wqb = xb  + X;   /* wqb,wkb,wvb,wob contiguous */
  unsigned short* wkb = wqb + W;
  unsigned short* wvb = wkb + W;
  unsigned short* wob = wvb + W;
  unsigned short* qb  = wob + W;
  unsigned short* kb  = qb  + X;
  unsigned short* vtg = kb  + X;
  unsigned short* ab  = vtg + X;

  cast_all<<<dim3(12288), 256, 0, stream>>>(x, wq, wk, wv, wo, xb, wqb);

  /* fused QKV: M=4096, N=6144, 256x192 tiles -> 16x32 = 512 blocks */
  gemm192<<<dim3(512), 512, 0, stream>>>(xb, wqb, bq, bk, bv, qb, kb, vtg);

  attn_fwd<<<dim3(512), 256, 0, stream>>>(qb, kb, vtg, ab);

  /* out-proj: M=4096, N=2048 -> 32x8 = 256 blocks (1 exact CU-round) */
  gemm256<<<dim3(256), 512, 0, stream>>>(ab, wob, bo, out, 1);
}